// Round 3
// baseline (109.188 us; speedup 1.0000x reference)
//
#include <hip/hip_runtime.h>
#include <hip/hip_bf16.h>

#define BN_EPS 1e-5f

typedef _Float16 half8 __attribute__((ext_vector_type(8)));
typedef _Float16 half4v __attribute__((ext_vector_type(4)));
typedef float f32x4v  __attribute__((ext_vector_type(4)));

static __device__ __forceinline__ float fmul(float a, float b){ return __fmul_rn(a,b); }
static __device__ __forceinline__ float fadd(float a, float b){ return __fadd_rn(a,b); }

// BN-stat accumulator banks: producers atomicAdd into bank (blockIdx & NB-1),
// consumers sum the banks in their prologue. Spreads atomic contention 16x/8x.
// layout (floats): s0[16*128] q0[16*128] s1[16*128] q1[16*128] s2[8*256] q2[8*256] = 12288
#define NB0 16
#define NB1 16
#define NB2 8

// ---------------- K1: ball query + ptsx build + xyz copy + weight pre-convert + stats zero ----------------
// blocks [0,4096): ball query; [4096,4672): ptsx build (16384 pts x 9 half8 rows:
//   k0..63 = feats, 64..66 = abs xyz, 67..71 = 0); [4672,4720): xyz->out copy;
//   4720: w0 frags; 4721: w1; 4722-3: w2; 4724: zero the 12288-float BN-stat banks.
__global__ __launch_bounds__(256) void bq_cvt_kernel(const float* __restrict__ xyz,
                                                     const float* __restrict__ pts,
                                                     const float* __restrict__ w0,
                                                     const float* __restrict__ w1,
                                                     const float* __restrict__ w2,
                                                     int* __restrict__ gidx,
                                                     half8* __restrict__ ptsx,
                                                     half8* __restrict__ w0fA,
                                                     half8* __restrict__ w0fB,
                                                     _Float16* __restrict__ w1h,
                                                     _Float16* __restrict__ w2h,
                                                     float* __restrict__ outbase,
                                                     float* __restrict__ stats)
{
    const int t = threadIdx.x;
    if (blockIdx.x >= 4720) {
        int wb = blockIdx.x - 4720;
        if (wb == 4) {
            for (int i = t; i < 12288; i += 256) stats[i] = 0.f;
            return;
        }
        if (wb == 0) {
            // w0 fragments: Wf[8][2][64] flat (k 0..63, src col k+3)
            for (int idx = t; idx < 1024; idx += 256) {
                int rg = idx >> 7, rem = idx & 127;
                int kk = rem >> 6, l = rem & 63;
                int row = rg*16 + (l & 15);
                int k0  = kk*32 + ((l >> 4) << 3);
                half8 v;
                #pragma unroll
                for (int e = 0; e < 8; ++e)
                    v[e] = (_Float16)w0[row*67 + k0 + e + 3];
                w0fA[idx] = v;
            }
            // Wf2 rows: [Wx,Wy,Wz, Wx,Wy,Wz, 0,0]  (k64..66 -> xg, k67..69 -> -xq)
            for (int idx = t; idx < 128; idx += 256) {
                int tile = idx >> 4, l = idx & 15;
                half8 v = {};
                v[0] = (_Float16)w0[idx*67 + 0];
                v[1] = (_Float16)w0[idx*67 + 1];
                v[2] = (_Float16)w0[idx*67 + 2];
                v[3] = v[0]; v[4] = v[1]; v[5] = v[2];
                w0fB[tile*17 + l] = v;
            }
            if (t < 8) { half8 z = {}; w0fB[t*17 + 16] = z; }
        } else if (wb == 1) {
            for (int i = t; i < 4096; i += 256) {       // w1: 16384 floats
                float4 v = ((const float4*)w1)[i];
                half4v h;
                h[0]=(_Float16)v.x; h[1]=(_Float16)v.y; h[2]=(_Float16)v.z; h[3]=(_Float16)v.w;
                ((half4v*)w1h)[i] = h;
            }
        } else {
            int i0 = (wb - 2) * 4096;
            for (int i = t; i < 4096; i += 256) {       // w2: 32768 floats, 2 blocks
                float4 v = ((const float4*)w2)[i0 + i];
                half4v h;
                h[0]=(_Float16)v.x; h[1]=(_Float16)v.y; h[2]=(_Float16)v.z; h[3]=(_Float16)v.w;
                ((half4v*)w2h)[i0 + i] = h;
            }
        }
        return;
    }
    if (blockIdx.x >= 4672) {                          // xyz -> out (new_xyz), 12288 float4
        int i = (blockIdx.x - 4672) * 256 + t;
        ((float4*)outbase)[i] = ((const float4*)xyz)[i];
        return;
    }
    if (blockIdx.x >= 4096) {                          // ptsx build: 147456 items
        int idx = (blockIdx.x - 4096) * 256 + t;
        int pt  = idx / 9;
        int grp = idx - pt * 9;
        if (grp < 8) {
            const float4* p4 = (const float4*)(pts + (size_t)pt*64 + grp*8);
            float4 a = p4[0], b4 = p4[1];
            half8 v;
            v[0]=(_Float16)a.x;  v[1]=(_Float16)a.y;  v[2]=(_Float16)a.z;  v[3]=(_Float16)a.w;
            v[4]=(_Float16)b4.x; v[5]=(_Float16)b4.y; v[6]=(_Float16)b4.z; v[7]=(_Float16)b4.w;
            ptsx[pt*9 + grp] = v;
        } else {
            const float* xg = xyz + (size_t)pt*3;
            half8 v = {};
            v[0]=(_Float16)xg[0]; v[1]=(_Float16)xg[1]; v[2]=(_Float16)xg[2];
            ptsx[pt*9 + 8] = v;
        }
        return;
    }
    const int lane = t & 63;
    const int wid  = t >> 6;
    const int q = blockIdx.x * 4 + wid;
    const int b = q >> 12;
    const int n = q & 4095;
    const float* xb = xyz + (size_t)b * 4096 * 3;
    const float qx = xb[n*3+0], qy = xb[n*3+1], qz = xb[n*3+2];
    const float sqn = fadd(fadd(fmul(qx,qx), fmul(qy,qy)), fmul(qz,qz));
    int* gout = gidx + q * 32;
    int count = 0;
    int first = -1;
    for (int base = 0; base < 4096 && count < 32; base += 64) {
        const int m = base + lane;
        const float mx = xb[m*3+0], my = xb[m*3+1], mz = xb[m*3+2];
        const float sqm = fadd(fadd(fmul(mx,mx), fmul(my,my)), fmul(mz,mz));
        const float e   = fadd(fadd(fmul(qx,mx), fmul(qy,my)), fmul(qz,mz));
        const float d   = __fsub_rn(fadd(sqn, sqm), fmul(2.0f, e));
        const bool in = !(d > 0.04f);               // ref: d > R^2 -> excluded
        const unsigned long long mask = __ballot(in);
        if (in) {
            int pos = count + __popcll(mask & ((1ull << lane) - 1ull));
            if (pos < 32) gout[pos] = m;
        }
        if (first < 0 && mask) first = base + __ffsll((unsigned long long)mask) - 1;
        count += __popcll(mask);
    }
    if (count < 32) {
        int slot = count + lane;
        if (slot < 32) gout[slot] = first;
    }
}

// ---------------- K2: conv0 (67->128) fp16 MFMA, direct register-fragment gather ----------------
// No LDS staging at all: operand layouts are fragment-ordered in memory, so each lane
// gathers its MFMA fragments straight from L2. Weights (w0fA/w0fB) live in registers for
// the whole kernel. rel-xyz via algebra: W*(g-q) = W*g + W*(-q); k64..66 = xg (from ptsx),
// k67..69 = -xq spliced in-register; weight cols 67..69 duplicate Wxyz. No __syncthreads
// in the main loop -> compiler pipelines gathers under MFMAs across unrolled iters.
// BN stats accumulate via banked device-scope fp32 atomics (bank = blockIdx & 15).
__global__ __launch_bounds__(256) void conv0_mfma_kernel(
    const float* __restrict__ xyz, const half8* __restrict__ ptsx,
    const int* __restrict__ gidx, const half8* __restrict__ w0fA, const half8* __restrict__ w0fB,
    const float* __restrict__ b0,
    float* __restrict__ s0a, float* __restrict__ q0a, _Float16* __restrict__ xm)
{
    __shared__ float psh[2][2][2][64];

    const int t    = threadIdx.x;
    const int lane = t & 63;
    const int wv   = t >> 6;
    const int wr   = wv >> 1;        // position half
    const int wc   = wv & 1;         // channel half
    const int lm   = lane & 15;
    const int lg   = lane >> 4;
    const int qbase = blockIdx.x * 16;
    const int bb    = qbase >> 12;

    // weights in registers for the whole kernel (fragment-ordered in memory)
    half8 wf[2][4];          // [kk][ci], k 0..63
    #pragma unroll
    for (int kk = 0; kk < 2; ++kk)
        #pragma unroll
        for (int ci = 0; ci < 4; ++ci)
            wf[kk][ci] = w0fA[(4*wc + ci)*128 + kk*64 + lane];
    half8 wf2[4];            // xyz-slice weights: lg==0 lanes carry data, others zero
    #pragma unroll
    for (int ci = 0; ci < 4; ++ci) {
        half8 z = {};
        wf2[ci] = (lg == 0) ? w0fB[(4*wc + ci)*17 + lm] : z;
    }

    float bv[4];
    #pragma unroll
    for (int ci = 0; ci < 4; ++ci) bv[ci] = b0[wc*64 + ci*16 + lm];

    float ssum[4], ssq[4];
    #pragma unroll
    for (int ci = 0; ci < 4; ++ci) { ssum[ci] = 0.f; ssq[ci] = 0.f; }

    #pragma unroll
    for (int it = 0; it < 4; ++it) {
        // per-lane fragment gather: tile pi row lm -> sample gidx[q*32+slot],
        // k-chunk kk*4+lg of the 144B ptsx row
        int gi[4];
        #pragma unroll
        for (int pi = 0; pi < 4; ++pi) {
            int q = qbase + it*4 + 2*wr + (pi >> 1);
            gi[pi] = gidx[(q << 5) + (pi & 1)*16 + lm];
        }
        half8 pf[2][4];      // [kk][pi]
        #pragma unroll
        for (int pi = 0; pi < 4; ++pi) {
            const half8* ps = ptsx + (size_t)((bb << 12) + gi[pi]) * 9;
            pf[0][pi] = ps[lg];
            pf[1][pi] = ps[4 + lg];
        }
        half8 pf2[4];        // xyz slice: lg==0 lanes carry [xg, -xq, 0,0], others zero
        #pragma unroll
        for (int pi = 0; pi < 4; ++pi) {
            half8 v = {};
            if (lg == 0) {
                const half8* ps = ptsx + (size_t)((bb << 12) + gi[pi]) * 9;
                v = ps[8];
                int q = qbase + it*4 + 2*wr + (pi >> 1);
                const float* xq = xyz + (size_t)((bb << 12) + (q & 4095)) * 3;
                v[3] = (_Float16)(-xq[0]);
                v[4] = (_Float16)(-xq[1]);
                v[5] = (_Float16)(-xq[2]);
            }
            pf2[pi] = v;
        }

        f32x4v acc[4][4];        // [pos-tile][ch-tile]
        #pragma unroll
        for (int pi = 0; pi < 4; ++pi)
            #pragma unroll
            for (int ci = 0; ci < 4; ++ci)
                #pragma unroll
                for (int j = 0; j < 4; ++j) acc[pi][ci][j] = bv[ci];

        #pragma unroll
        for (int kk = 0; kk < 2; ++kk)
            #pragma unroll
            for (int pi = 0; pi < 4; ++pi)
                #pragma unroll
                for (int ci = 0; ci < 4; ++ci)
                    acc[pi][ci] = __builtin_amdgcn_mfma_f32_16x16x32_f16(pf[kk][pi], wf[kk][ci], acc[pi][ci], 0, 0, 0);
        #pragma unroll
        for (int pi = 0; pi < 4; ++pi)
            #pragma unroll
            for (int ci = 0; ci < 4; ++ci)
                acc[pi][ci] = __builtin_amdgcn_mfma_f32_16x16x32_f16(pf2[pi], wf2[ci], acc[pi][ci], 0, 0, 0);

        // stats + maxpool; coalesced xm stores (each lg group stores its own ci channel)
        float vA[4], vB[4];
        #pragma unroll
        for (int ci = 0; ci < 4; ++ci) {
            float a = acc[0][ci][0], bmx = acc[2][ci][0];
            #pragma unroll
            for (int j = 0; j < 4; ++j) {
                float a0 = acc[0][ci][j], a1 = acc[1][ci][j];
                float a2 = acc[2][ci][j], a3 = acc[3][ci][j];
                ssum[ci] += ((a0 + a1) + (a2 + a3));
                ssq[ci] = fmaf(a0, a0, ssq[ci]);
                ssq[ci] = fmaf(a1, a1, ssq[ci]);
                ssq[ci] = fmaf(a2, a2, ssq[ci]);
                ssq[ci] = fmaf(a3, a3, ssq[ci]);
                a   = fmaxf(a,   fmaxf(a0, a1));
                bmx = fmaxf(bmx, fmaxf(a2, a3));
            }
            a   = fmaxf(a,   __shfl_xor(a, 16));   a   = fmaxf(a,   __shfl_xor(a, 32));
            bmx = fmaxf(bmx, __shfl_xor(bmx, 16)); bmx = fmaxf(bmx, __shfl_xor(bmx, 32));
            vA[ci] = a; vB[ci] = bmx;
        }
        float fa = (lg == 0) ? vA[0] : (lg == 1) ? vA[1] : (lg == 2) ? vA[2] : vA[3];
        float fb = (lg == 0) ? vB[0] : (lg == 1) ? vB[1] : (lg == 2) ? vB[2] : vB[3];
        const int nA = (qbase + it*4 + wr*2) & 4095;
        const int ch = wc*64 + lg*16 + lm;             // = wc*64 + lane: 128B contiguous store
        xm[((size_t)((bb << 12) + nA)     << 7) + ch] = (_Float16)fa;
        xm[((size_t)((bb << 12) + nA + 1) << 7) + ch] = (_Float16)fb;
    }

    // per-block partial -> banked atomic accumulate (order noise ~2^-23 rel, harmless)
    #pragma unroll
    for (int ci = 0; ci < 4; ++ci) {
        float s  = ssum[ci];
        float s2 = ssq[ci];
        s  += __shfl_xor(s, 16);  s  += __shfl_xor(s, 32);
        s2 += __shfl_xor(s2, 16); s2 += __shfl_xor(s2, 32);
        if (lg == 0) {
            psh[0][wr][wc][ci*16 + lm] = s;
            psh[1][wr][wc][ci*16 + lm] = s2;
        }
    }
    __syncthreads();
    if (t < 128) {
        const int bank = blockIdx.x & (NB0 - 1);
        atomicAdd(&s0a[bank*128 + t], psh[0][0][t >> 6][t & 63] + psh[0][1][t >> 6][t & 63]);
        atomicAdd(&q0a[bank*128 + t], psh[1][0][t >> 6][t & 63] + psh[1][1][t >> 6][t & 63]);
    }
}

// ---------------- conv1/conv2 fp16 MFMA, position-major fp16 IO, BN(in)+ReLU fused ----------------
// Input-layer BN scale/shift computed per-block from the 16 input stat banks (L2-hit).
// Output stats accumulate into NBOUT banked atomics.
template<int OC, int NBOUT>
__global__ __launch_bounds__(256) void conv12_mfma_kernel(
    const _Float16* __restrict__ x, const _Float16* __restrict__ wh, const float* __restrict__ bias,
    const float* __restrict__ inS, const float* __restrict__ inQ,
    const float* __restrict__ gamma, const float* __restrict__ beta, float invc,
    _Float16* __restrict__ y, float* __restrict__ outS, float* __restrict__ outQ)
{
    __shared__ half8 Wf[8][4][64];            // 32KB
    __shared__ half8 Xf[4][4][64];            // 16KB
    __shared__ float scs[128], shs[128];
    __shared__ float psh[2][2][2][64];

    const int t = threadIdx.x, lane = t & 63, wv = t >> 6;
    const int wr = wv >> 1, wc = wv & 1;
    const int lm = lane & 15, lg = lane >> 4;
    const int n0 = blockIdx.x * 64;
    const int rb = blockIdx.y * 128;
    const int b  = blockIdx.z;

    if (t < 128) {                      // finalize input-layer BN from banked sums
        float s = 0.f, q = 0.f;
        #pragma unroll
        for (int k = 0; k < NB0; ++k) { s += inS[k*128 + t]; q += inQ[k*128 + t]; }
        float m = s * invc;
        float v = q * invc - m*m;
        float scale = gamma[t] * rsqrtf(v + BN_EPS);
        scs[t] = scale;
        shs[t] = beta[t] - m * scale;
    }
    __syncthreads();

    for (int idx = t; idx < 8*4*64; idx += 256) {
        int rg = idx >> 8, rem = idx & 255;
        int kk = rem >> 6, l = rem & 63;
        int row = rb + rg*16 + (l & 15);
        int k0  = kk*32 + (l >> 4)*8;
        Wf[rg][kk][l] = *(const half8*)(wh + row*128 + k0);
    }
    for (int idx = t; idx < 4*4*64; idx += 256) {
        int ng = idx >> 8, rem = idx & 255;
        int kk = rem >> 6, l = rem & 63;
        int n  = n0 + ng*16 + (l & 15);
        int c0 = kk*32 + (l >> 4)*8;
        half8 xv = *(const half8*)(x + (((size_t)((b << 12) + n)) << 7) + c0);
        half8 v;
        #pragma unroll
        for (int e = 0; e < 8; ++e)
            v[e] = (_Float16)fmaxf(fmaf((float)xv[e], scs[c0+e], shs[c0+e]), 0.f);
        Xf[ng][kk][l] = v;
    }
    __syncthreads();

    f32x4v acc[2][4];
    #pragma unroll
    for (int ci = 0; ci < 4; ++ci) {
        float bvv = bias[rb + wc*64 + ci*16 + lm];
        #pragma unroll
        for (int pi = 0; pi < 2; ++pi)
            #pragma unroll
            for (int j = 0; j < 4; ++j) acc[pi][ci][j] = bvv;
    }
    #pragma unroll
    for (int kk = 0; kk < 4; ++kk) {
        half8 pf[2], wf[4];
        #pragma unroll
        for (int pi = 0; pi < 2; ++pi) pf[pi] = Xf[2*wr + pi][kk][lane];
        #pragma unroll
        for (int ci = 0; ci < 4; ++ci) wf[ci] = Wf[4*wc + ci][kk][lane];
        #pragma unroll
        for (int pi = 0; pi < 2; ++pi)
            #pragma unroll
            for (int ci = 0; ci < 4; ++ci)
                acc[pi][ci] = __builtin_amdgcn_mfma_f32_16x16x32_f16(pf[pi], wf[ci], acc[pi][ci], 0, 0, 0);
    }

    float ssum[4], ssq[4];
    #pragma unroll
    for (int ci = 0; ci < 4; ++ci) { ssum[ci] = 0.f; ssq[ci] = 0.f; }
    #pragma unroll
    for (int pi = 0; pi < 2; ++pi) {
        #pragma unroll
        for (int j = 0; j < 4; ++j) {
            int n = n0 + wr*32 + pi*16 + lg*4 + j;
            size_t basep = (size_t)((b << 12) + n) * OC + rb;
            #pragma unroll
            for (int ci = 0; ci < 4; ++ci) {
                float v = acc[pi][ci][j];
                y[basep + wc*64 + ci*16 + lm] = (_Float16)v;
                ssum[ci] += v;
                ssq[ci]  = fmaf(v, v, ssq[ci]);
            }
        }
    }
    #pragma unroll
    for (int ci = 0; ci < 4; ++ci) {
        float s  = ssum[ci], s2 = ssq[ci];
        s  += __shfl_xor(s, 16);  s  += __shfl_xor(s, 32);
        s2 += __shfl_xor(s2, 16); s2 += __shfl_xor(s2, 32);
        if (lg == 0) {
            psh[0][wr][wc][ci*16 + lm] = s;
            psh[1][wr][wc][ci*16 + lm] = s2;
        }
    }
    __syncthreads();
    if (t < 128) {
        const int bank = (blockIdx.x + blockIdx.y + (blockIdx.z << 2)) & (NBOUT - 1);
        atomicAdd(&outS[(size_t)bank*OC + rb + t], psh[0][0][t >> 6][t & 63] + psh[0][1][t >> 6][t & 63]);
        atomicAdd(&outQ[(size_t)bank*OC + rb + t], psh[1][0][t >> 6][t & 63] + psh[1][1][t >> 6][t & 63]);
    }
}

// ---------------- final: BN2 finalize (from banked sums) + ReLU on y2h -> out fp32 ----------------
__global__ __launch_bounds__(256) void final_apply_kernel(const _Float16* __restrict__ y2h,
                                                          const float* __restrict__ s2a,
                                                          const float* __restrict__ q2a,
                                                          const float* __restrict__ gamma,
                                                          const float* __restrict__ beta,
                                                          float invc,
                                                          float* __restrict__ outbase)
{
    __shared__ float scs[256], shs[256];
    const int t = threadIdx.x;
    {
        float s = 0.f, q = 0.f;
        #pragma unroll
        for (int k = 0; k < NB2; ++k) { s += s2a[k*256 + t]; q += q2a[k*256 + t]; }
        float m = s * invc;
        float v = q * invc - m*m;
        float scale = gamma[t] * rsqrtf(v + BN_EPS);
        scs[t] = scale;
        shs[t] = beta[t] - m * scale;
    }
    __syncthreads();
    int i = blockIdx.x * 256 + t;                  // half8 index, [0, 524288)
    half8 v = ((const half8*)y2h)[i];
    int c0 = (i & 31) * 8;
    float4 o0, o1;
    o0.x = fmaxf(fmaf((float)v[0], scs[c0+0], shs[c0+0]), 0.f);
    o0.y = fmaxf(fmaf((float)v[1], scs[c0+1], shs[c0+1]), 0.f);
    o0.z = fmaxf(fmaf((float)v[2], scs[c0+2], shs[c0+2]), 0.f);
    o0.w = fmaxf(fmaf((float)v[3], scs[c0+3], shs[c0+3]), 0.f);
    o1.x = fmaxf(fmaf((float)v[4], scs[c0+4], shs[c0+4]), 0.f);
    o1.y = fmaxf(fmaf((float)v[5], scs[c0+5], shs[c0+5]), 0.f);
    o1.z = fmaxf(fmaf((float)v[6], scs[c0+6], shs[c0+6]), 0.f);
    o1.w = fmaxf(fmaf((float)v[7], scs[c0+7], shs[c0+7]), 0.f);
    float4* op = (float4*)(outbase + 49152);
    op[2*i]   = o0;
    op[2*i+1] = o1;
}

extern "C" void kernel_launch(void* const* d_in, const int* in_sizes, int n_in,
                              void* d_out, int out_size, void* d_ws, size_t ws_size,
                              hipStream_t stream)
{
    const float* xyz = (const float*)d_in[0];
    const float* pts = (const float*)d_in[1];
    const float* w0  = (const float*)d_in[2];
    const float* b0  = (const float*)d_in[3];
    const float* g0  = (const float*)d_in[4];
    const float* bt0 = (const float*)d_in[5];
    const float* w1  = (const float*)d_in[6];
    const float* b1  = (const float*)d_in[7];
    const float* g1  = (const float*)d_in[8];
    const float* bt1 = (const float*)d_in[9];
    const float* w2  = (const float*)d_in[10];
    const float* b2  = (const float*)d_in[11];
    const float* g2  = (const float*)d_in[12];
    const float* bt2 = (const float*)d_in[13];
    float* out = (float*)d_out;

    // Layout (peak ~24.2MB): gidx [0,2) ptsx [2,4.5) xm [4.5,8.5) y1 [8.5,12.5)
    //                        y2 [12.5,20.5) stats [~22.3) W [24,24.2)
    char* ws = (char*)d_ws;
    int*      gidx = (int*)ws;
    half8*    ptsx = (half8*)(ws + 2097152);
    _Float16* xmh  = (_Float16*)(ws + 4718592);
    _Float16* y1h  = (_Float16*)(ws + 8912896);
    _Float16* y2h  = (_Float16*)(ws + 13107200);
    float*    stb  = (float*)(ws + 21495808);        // 12288-float banked BN-stat block
    float *s0a = stb,        *q0a = stb + 2048;      // 16 banks x 128, layer0 count 524288
    float *s1a = stb + 4096, *q1a = stb + 6144;      // 16 banks x 128, layer1 count 16384
    float *s2a = stb + 8192, *q2a = stb + 10240;     // 8 banks x 256, layer2 count 16384
    char*     wb   = ws + (24u << 20);
    half8*    w0fA = (half8*)wb;                     // 16384 B
    half8*    w0fB = (half8*)(wb + 16384);           // 2176 B
    _Float16* w1h  = (_Float16*)(wb + 32768);        // 32768 B
    _Float16* w2h  = (_Float16*)(wb + 98304);        // 65536 B

    bq_cvt_kernel<<<4725, 256, 0, stream>>>(xyz, pts, w0, w1, w2, gidx, ptsx,
                                            w0fA, w0fB, w1h, w2h, out, stb);
    conv0_mfma_kernel<<<1024, 256, 0, stream>>>(xyz, ptsx, gidx, w0fA, w0fB, b0,
                                                s0a, q0a, xmh);
    conv12_mfma_kernel<128, NB1><<<dim3(64,1,4), 256, 0, stream>>>(xmh, w1h, b1, s0a, q0a,
                                                                   g0, bt0, 1.f/524288.f,
                                                                   y1h, s1a, q1a);
    conv12_mfma_kernel<256, NB2><<<dim3(64,2,4), 256, 0, stream>>>(y1h, w2h, b2, s1a, q1a,
                                                                   g1, bt1, 1.f/16384.f,
                                                                   y2h, s2a, q2a);
    final_apply_kernel<<<2048, 256, 0, stream>>>(y2h, s2a, q2a, g2, bt2, 1.f/16384.f, out);
}

// Round 5
// 81.723 us; speedup vs baseline: 1.3361x; 1.3361x over previous
//
#include <hip/hip_runtime.h>
#include <hip/hip_bf16.h>

#define BN_EPS 1e-5f

typedef _Float16 half8 __attribute__((ext_vector_type(8)));
typedef _Float16 half4v __attribute__((ext_vector_type(4)));
typedef _Float16 half2v __attribute__((ext_vector_type(2)));
typedef float f32x4v  __attribute__((ext_vector_type(4)));

static __device__ __forceinline__ float fmul(float a, float b){ return __fmul_rn(a,b); }
static __device__ __forceinline__ float fadd(float a, float b){ return __fadd_rn(a,b); }

// BN-stat accumulator banks: producers atomicAdd into bank (blockIdx & NB-1),
// consumers sum the banks in their prologue. Spreads atomic contention 16x/8x.
// layout (floats): s0[16*128] q0[16*128] s1[16*128] q1[16*128] s2[8*256] q2[8*256] = 12288
#define NB0 16
#define NB1 16
#define NB2 8

// ---------------- K1: ball query + ptsx build + xyz copy + weight pre-convert + stats zero ----------------
// blocks [0,4096): ball query; [4096,4672): ptsx build (16384 pts x 9 half8 rows:
//   k0..63 = feats, 64..66 = abs xyz, 67..71 = 0); [4672,4720): xyz->out copy;
//   4720: w0 frags + wcq table; 4721: w1; 4722-3: w2; 4724: zero the BN-stat banks.
__global__ __launch_bounds__(256) void bq_cvt_kernel(const float* __restrict__ xyz,
                                                     const float* __restrict__ pts,
                                                     const float* __restrict__ w0,
                                                     const float* __restrict__ w1,
                                                     const float* __restrict__ w2,
                                                     const float* __restrict__ b0,
                                                     int* __restrict__ gidx,
                                                     half8* __restrict__ ptsx,
                                                     half8* __restrict__ w0fA,
                                                     half8* __restrict__ w0fB,
                                                     _Float16* __restrict__ w1h,
                                                     _Float16* __restrict__ w2h,
                                                     float4* __restrict__ wcq,
                                                     float* __restrict__ outbase,
                                                     float* __restrict__ stats)
{
    const int t = threadIdx.x;
    if (blockIdx.x >= 4720) {
        int wb = blockIdx.x - 4720;
        if (wb == 4) {
            for (int i = t; i < 12288; i += 256) stats[i] = 0.f;
            return;
        }
        if (wb == 0) {
            // w0 fragments: Wf[8][2][64] flat (k 0..63, src col k+3)
            for (int idx = t; idx < 1024; idx += 256) {
                int rg = idx >> 7, rem = idx & 127;
                int kk = rem >> 6, l = rem & 63;
                int row = rg*16 + (l & 15);
                int k0  = kk*32 + ((l >> 4) << 3);
                half8 v;
                #pragma unroll
                for (int e = 0; e < 8; ++e)
                    v[e] = (_Float16)w0[row*67 + k0 + e + 3];
                w0fA[idx] = v;
            }
            // Wf2 rows: [Wx,Wy,Wz, 0,0,0, 0,0]  (k64..66 -> xg; -xq handled analytically in pool)
            // + wcq table: per channel {Wx,Wy,Wz (fp16-rounded), b0} fp32 for the pool kernel
            for (int idx = t; idx < 128; idx += 256) {
                half8 v = {};
                v[0] = (_Float16)w0[idx*67 + 0];
                v[1] = (_Float16)w0[idx*67 + 1];
                v[2] = (_Float16)w0[idx*67 + 2];
                int tile = idx >> 4, l = idx & 15;
                w0fB[tile*17 + l] = v;
                wcq[idx] = make_float4((float)v[0], (float)v[1], (float)v[2], b0[idx]);
            }
            if (t < 8) { half8 z = {}; w0fB[t*17 + 16] = z; }
        } else if (wb == 1) {
            for (int i = t; i < 4096; i += 256) {       // w1: 16384 floats
                float4 v = ((const float4*)w1)[i];
                half4v h;
                h[0]=(_Float16)v.x; h[1]=(_Float16)v.y; h[2]=(_Float16)v.z; h[3]=(_Float16)v.w;
                ((half4v*)w1h)[i] = h;
            }
        } else {
            int i0 = (wb - 2) * 4096;
            for (int i = t; i < 4096; i += 256) {       // w2: 32768 floats, 2 blocks
                float4 v = ((const float4*)w2)[i0 + i];
                half4v h;
                h[0]=(_Float16)v.x; h[1]=(_Float16)v.y; h[2]=(_Float16)v.z; h[3]=(_Float16)v.w;
                ((half4v*)w2h)[i0 + i] = h;
            }
        }
        return;
    }
    if (blockIdx.x >= 4672) {                          // xyz -> out (new_xyz), 12288 float4
        int i = (blockIdx.x - 4672) * 256 + t;
        ((float4*)outbase)[i] = ((const float4*)xyz)[i];
        return;
    }
    if (blockIdx.x >= 4096) {                          // ptsx build: 147456 items
        int idx = (blockIdx.x - 4096) * 256 + t;
        int pt  = idx / 9;
        int grp = idx - pt * 9;
        if (grp < 8) {
            const float4* p4 = (const float4*)(pts + (size_t)pt*64 + grp*8);
            float4 a = p4[0], b4 = p4[1];
            half8 v;
            v[0]=(_Float16)a.x;  v[1]=(_Float16)a.y;  v[2]=(_Float16)a.z;  v[3]=(_Float16)a.w;
            v[4]=(_Float16)b4.x; v[5]=(_Float16)b4.y; v[6]=(_Float16)b4.z; v[7]=(_Float16)b4.w;
            ptsx[pt*9 + grp] = v;
        } else {
            const float* xg = xyz + (size_t)pt*3;
            half8 v = {};
            v[0]=(_Float16)xg[0]; v[1]=(_Float16)xg[1]; v[2]=(_Float16)xg[2];
            ptsx[pt*9 + 8] = v;
        }
        return;
    }
    const int lane = t & 63;
    const int wid  = t >> 6;
    const int q = blockIdx.x * 4 + wid;
    const int b = q >> 12;
    const int n = q & 4095;
    const float* xb = xyz + (size_t)b * 4096 * 3;
    const float qx = xb[n*3+0], qy = xb[n*3+1], qz = xb[n*3+2];
    const float sqn = fadd(fadd(fmul(qx,qx), fmul(qy,qy)), fmul(qz,qz));
    int* gout = gidx + q * 32;
    int count = 0;
    int first = -1;
    for (int base = 0; base < 4096 && count < 32; base += 64) {
        const int m = base + lane;
        const float mx = xb[m*3+0], my = xb[m*3+1], mz = xb[m*3+2];
        const float sqm = fadd(fadd(fmul(mx,mx), fmul(my,my)), fmul(mz,mz));
        const float e   = fadd(fadd(fmul(qx,mx), fmul(qy,my)), fmul(qz,mz));
        const float d   = __fsub_rn(fadd(sqn, sqm), fmul(2.0f, e));
        const bool in = !(d > 0.04f);               // ref: d > R^2 -> excluded
        const unsigned long long mask = __ballot(in);
        if (in) {
            int pos = count + __popcll(mask & ((1ull << lane) - 1ull));
            if (pos < 32) gout[pos] = m;
        }
        if (first < 0 && mask) first = base + __ffsll((unsigned long long)mask) - 1;
        count += __popcll(mask);
    }
    if (count < 32) {
        int slot = count + lane;
        if (slot < 32) gout[slot] = first;
    }
}

// ---------------- K1b: dense per-point transform Ypt[pt] = W0 * feat(pt)  (16384 x 72 -> 128) ----------------
// The gather in conv0 commutes with the linear map: do the matmul densely (coalesced,
// contiguous ptsx rows), let the pool kernel gather the 128-ch OUTPUT rows instead.
// No bias (added analytically in pool). 24 MFMAs/wave, one shot.
__global__ __launch_bounds__(256) void ypt_kernel(const half8* __restrict__ ptsx,
                                                  const half8* __restrict__ w0fA,
                                                  const half8* __restrict__ w0fB,
                                                  _Float16* __restrict__ ypt)
{
    __shared__ half8 FL[578];      // 64 rows x 9 chunks, [576] = zero row
    __shared__ half8 WfL[1024];
    __shared__ half8 W2L[136];

    const int t = threadIdx.x, lane = t & 63, wv = t >> 6;
    const int wr = wv >> 1, wc = wv & 1;
    const int lm = lane & 15, lg = lane >> 4;
    const int i2 = (lg == 0) ? lm : 16;
    const int p0 = blockIdx.x * 64;

    for (int i = t; i < 1024; i += 256) WfL[i] = w0fA[i];
    for (int i = t; i < 136; i += 256)  W2L[i] = w0fB[i];
    for (int i = t; i < 577; i += 256) {
        half8 z = {};
        FL[i] = (i < 576) ? ptsx[(size_t)p0*9 + i] : z;
    }
    __syncthreads();

    f32x4v acc[2][4];
    #pragma unroll
    for (int pi = 0; pi < 2; ++pi)
        #pragma unroll
        for (int ci = 0; ci < 4; ++ci)
            #pragma unroll
            for (int j = 0; j < 4; ++j) acc[pi][ci][j] = 0.f;

    #pragma unroll
    for (int kk = 0; kk < 2; ++kk) {
        half8 pf[2], wf[4];
        #pragma unroll
        for (int pi = 0; pi < 2; ++pi) pf[pi] = FL[(wr*32 + pi*16 + lm)*9 + kk*4 + lg];
        #pragma unroll
        for (int ci = 0; ci < 4; ++ci) wf[ci] = WfL[(4*wc + ci)*128 + kk*64 + lane];
        #pragma unroll
        for (int pi = 0; pi < 2; ++pi)
            #pragma unroll
            for (int ci = 0; ci < 4; ++ci)
                acc[pi][ci] = __builtin_amdgcn_mfma_f32_16x16x32_f16(pf[pi], wf[ci], acc[pi][ci], 0, 0, 0);
    }
    {   // abs-xyz slice (k64..66); lg>0 lanes read zero rows on both operands
        half8 pf[2], wf[4];
        #pragma unroll
        for (int pi = 0; pi < 2; ++pi)
            pf[pi] = FL[(lg == 0) ? ((wr*32 + pi*16 + lm)*9 + 8) : 576];
        #pragma unroll
        for (int ci = 0; ci < 4; ++ci) wf[ci] = W2L[(4*wc + ci)*17 + i2];
        #pragma unroll
        for (int pi = 0; pi < 2; ++pi)
            #pragma unroll
            for (int ci = 0; ci < 4; ++ci)
                acc[pi][ci] = __builtin_amdgcn_mfma_f32_16x16x32_f16(pf[pi], wf[ci], acc[pi][ci], 0, 0, 0);
    }

    #pragma unroll
    for (int pi = 0; pi < 2; ++pi) {
        #pragma unroll
        for (int j = 0; j < 4; ++j) {
            int n = p0 + wr*32 + pi*16 + lg*4 + j;
            size_t basep = (size_t)n * 128;
            #pragma unroll
            for (int ci = 0; ci < 4; ++ci)
                ypt[basep + wc*64 + ci*16 + lm] = (_Float16)acc[pi][ci][j];
        }
    }
}

// ---------------- K2: gather-pool-stats (replaces conv0's gather+MFMA) ----------------
// Per q: value(q,s,c) = Ypt[gidx[q,s]][c] + c_q[c],  c_q = b0 - Wxyz . xq.
// maxpool: max_s(Ypt)+c_q (c_q slot-independent); BN stats analytically:
// sum = SUM Y + 32c, sumsq = SUM Y^2 + 2c SUM Y + 32c^2. One wave per q, lane owns 2 ch;
// each slot read is a fully-coalesced 256B row from the 4MB L2-resident Ypt.
__global__ __launch_bounds__(256) void pool_stats_kernel(
    const _Float16* __restrict__ ypt, const int* __restrict__ gidx,
    const float4* __restrict__ wcq, const float* __restrict__ xyz,
    float* __restrict__ s0a, float* __restrict__ q0a, _Float16* __restrict__ xm)
{
    __shared__ float psh[2][4][128];
    const int t = threadIdx.x, lane = t & 63, wv = t >> 6;
    const float4 wA = wcq[2*lane], wB = wcq[2*lane + 1];
    const half2v* Y2 = (const half2v*)ypt;
    float ss0 = 0.f, ss1 = 0.f, qq0 = 0.f, qq1 = 0.f;

    #pragma unroll
    for (int e = 0; e < 4; ++e) {
        const int q  = blockIdx.x * 16 + wv * 4 + e;
        const int gi = gidx[(q << 5) + (lane & 31)];
        const float* xq = xyz + (size_t)q * 3;
        const float x0 = xq[0], x1 = xq[1], x2 = xq[2];
        const float cA = wA.w - (wA.x*x0 + wA.y*x1 + wA.z*x2);
        const float cB = wB.w - (wB.x*x0 + wB.y*x1 + wB.z*x2);
        const size_t rbase = (size_t)(q >> 12) << 12;

        float m0 = -3.4e38f, m1 = -3.4e38f;
        float sy0 = 0.f, sy1 = 0.f, yy0 = 0.f, yy1 = 0.f;
        #pragma unroll 8
        for (int s = 0; s < 32; ++s) {
            int g = __shfl(gi, s);
            half2v h = Y2[(rbase + g)*64 + lane];
            float y0 = (float)h[0], y1 = (float)h[1];
            m0 = fmaxf(m0, y0); m1 = fmaxf(m1, y1);
            sy0 += y0; sy1 += y1;
            yy0 = fmaf(y0, y0, yy0); yy1 = fmaf(y1, y1, yy1);
        }
        half2v ov;
        ov[0] = (_Float16)(m0 + cA);
        ov[1] = (_Float16)(m1 + cB);
        ((half2v*)xm)[(size_t)q*64 + lane] = ov;

        ss0 += sy0 + 32.f*cA;
        ss1 += sy1 + 32.f*cB;
        qq0 += yy0 + 2.f*cA*sy0 + 32.f*cA*cA;
        qq1 += yy1 + 2.f*cB*sy1 + 32.f*cB*cB;
    }

    psh[0][wv][2*lane] = ss0; psh[0][wv][2*lane+1] = ss1;
    psh[1][wv][2*lane] = qq0; psh[1][wv][2*lane+1] = qq1;
    __syncthreads();
    if (t < 128) {
        const int bank = blockIdx.x & (NB0 - 1);
        float s  = psh[0][0][t] + psh[0][1][t] + psh[0][2][t] + psh[0][3][t];
        float qv = psh[1][0][t] + psh[1][1][t] + psh[1][2][t] + psh[1][3][t];
        atomicAdd(&s0a[bank*128 + t], s);
        atomicAdd(&q0a[bank*128 + t], qv);
    }
}

// ---------------- conv1/conv2 fp16 MFMA, position-major fp16 IO, BN(in)+ReLU fused ----------------
// Input-layer BN scale/shift computed per-block from the 16 input stat banks (L2-hit).
// Output stats accumulate into NBOUT banked atomics.
template<int OC, int NBOUT>
__global__ __launch_bounds__(256) void conv12_mfma_kernel(
    const _Float16* __restrict__ x, const _Float16* __restrict__ wh, const float* __restrict__ bias,
    const float* __restrict__ inS, const float* __restrict__ inQ,
    const float* __restrict__ gamma, const float* __restrict__ beta, float invc,
    _Float16* __restrict__ y, float* __restrict__ outS, float* __restrict__ outQ)
{
    __shared__ half8 Wf[8][4][64];            // 32KB
    __shared__ half8 Xf[4][4][64];            // 16KB
    __shared__ float scs[128], shs[128];
    __shared__ float psh[2][2][2][64];

    const int t = threadIdx.x, lane = t & 63, wv = t >> 6;
    const int wr = wv >> 1, wc = wv & 1;
    const int lm = lane & 15, lg = lane >> 4;
    const int n0 = blockIdx.x * 64;
    const int rb = blockIdx.y * 128;
    const int b  = blockIdx.z;

    if (t < 128) {                      // finalize input-layer BN from banked sums
        float s = 0.f, q = 0.f;
        #pragma unroll
        for (int k = 0; k < NB0; ++k) { s += inS[k*128 + t]; q += inQ[k*128 + t]; }
        float m = s * invc;
        float v = q * invc - m*m;
        float scale = gamma[t] * rsqrtf(v + BN_EPS);
        scs[t] = scale;
        shs[t] = beta[t] - m * scale;
    }
    __syncthreads();

    for (int idx = t; idx < 8*4*64; idx += 256) {
        int rg = idx >> 8, rem = idx & 255;
        int kk = rem >> 6, l = rem & 63;
        int row = rb + rg*16 + (l & 15);
        int k0  = kk*32 + (l >> 4)*8;
        Wf[rg][kk][l] = *(const half8*)(wh + row*128 + k0);
    }
    for (int idx = t; idx < 4*4*64; idx += 256) {
        int ng = idx >> 8, rem = idx & 255;
        int kk = rem >> 6, l = rem & 63;
        int n  = n0 + ng*16 + (l & 15);
        int c0 = kk*32 + (l >> 4)*8;
        half8 xv = *(const half8*)(x + (((size_t)((b << 12) + n)) << 7) + c0);
        half8 v;
        #pragma unroll
        for (int e = 0; e < 8; ++e)
            v[e] = (_Float16)fmaxf(fmaf((float)xv[e], scs[c0+e], shs[c0+e]), 0.f);
        Xf[ng][kk][l] = v;
    }
    __syncthreads();

    f32x4v acc[2][4];
    #pragma unroll
    for (int ci = 0; ci < 4; ++ci) {
        float bvv = bias[rb + wc*64 + ci*16 + lm];
        #pragma unroll
        for (int pi = 0; pi < 2; ++pi)
            #pragma unroll
            for (int j = 0; j < 4; ++j) acc[pi][ci][j] = bvv;
    }
    #pragma unroll
    for (int kk = 0; kk < 4; ++kk) {
        half8 pf[2], wf[4];
        #pragma unroll
        for (int pi = 0; pi < 2; ++pi) pf[pi] = Xf[2*wr + pi][kk][lane];
        #pragma unroll
        for (int ci = 0; ci < 4; ++ci) wf[ci] = Wf[4*wc + ci][kk][lane];
        #pragma unroll
        for (int pi = 0; pi < 2; ++pi)
            #pragma unroll
            for (int ci = 0; ci < 4; ++ci)
                acc[pi][ci] = __builtin_amdgcn_mfma_f32_16x16x32_f16(pf[pi], wf[ci], acc[pi][ci], 0, 0, 0);
    }

    float ssum[4], ssq[4];
    #pragma unroll
    for (int ci = 0; ci < 4; ++ci) { ssum[ci] = 0.f; ssq[ci] = 0.f; }
    #pragma unroll
    for (int pi = 0; pi < 2; ++pi) {
        #pragma unroll
        for (int j = 0; j < 4; ++j) {
            int n = n0 + wr*32 + pi*16 + lg*4 + j;
            size_t basep = (size_t)((b << 12) + n) * OC + rb;
            #pragma unroll
            for (int ci = 0; ci < 4; ++ci) {
                float v = acc[pi][ci][j];
                y[basep + wc*64 + ci*16 + lm] = (_Float16)v;
                ssum[ci] += v;
                ssq[ci]  = fmaf(v, v, ssq[ci]);
            }
        }
    }
    #pragma unroll
    for (int ci = 0; ci < 4; ++ci) {
        float s  = ssum[ci], s2 = ssq[ci];
        s  += __shfl_xor(s, 16);  s  += __shfl_xor(s, 32);
        s2 += __shfl_xor(s2, 16); s2 += __shfl_xor(s2, 32);
        if (lg == 0) {
            psh[0][wr][wc][ci*16 + lm] = s;
            psh[1][wr][wc][ci*16 + lm] = s2;
        }
    }
    __syncthreads();
    if (t < 128) {
        const int bank = (blockIdx.x + blockIdx.y + (blockIdx.z << 2)) & (NBOUT - 1);
        atomicAdd(&outS[(size_t)bank*OC + rb + t], psh[0][0][t >> 6][t & 63] + psh[0][1][t >> 6][t & 63]);
        atomicAdd(&outQ[(size_t)bank*OC + rb + t], psh[1][0][t >> 6][t & 63] + psh[1][1][t >> 6][t & 63]);
    }
}

// ---------------- final: BN2 finalize (from banked sums) + ReLU on y2h -> out fp32 ----------------
__global__ __launch_bounds__(256) void final_apply_kernel(const _Float16* __restrict__ y2h,
                                                          const float* __restrict__ s2a,
                                                          const float* __restrict__ q2a,
                                                          const float* __restrict__ gamma,
                                                          const float* __restrict__ beta,
                                                          float invc,
                                                          float* __restrict__ outbase)
{
    __shared__ float scs[256], shs[256];
    const int t = threadIdx.x;
    {
        float s = 0.f, q = 0.f;
        #pragma unroll
        for (int k = 0; k < NB2; ++k) { s += s2a[k*256 + t]; q += q2a[k*256 + t]; }
        float m = s * invc;
        float v = q * invc - m*m;
        float scale = gamma[t] * rsqrtf(v + BN_EPS);
        scs[t] = scale;
        shs[t] = beta[t] - m * scale;
    }
    __syncthreads();
    int i = blockIdx.x * 256 + t;                  // half8 index, [0, 524288)
    half8 v = ((const half8*)y2h)[i];
    int c0 = (i & 31) * 8;
    float4 o0, o1;
    o0.x = fmaxf(fmaf((float)v[0], scs[c0+0], shs[c0+0]), 0.f);
    o0.y = fmaxf(fmaf((float)v[1], scs[c0+1], shs[c0+1]), 0.f);
    o0.z = fmaxf(fmaf((float)v[2], scs[c0+2], shs[c0+2]), 0.f);
    o0.w = fmaxf(fmaf((float)v[3], scs[c0+3], shs[c0+3]), 0.f);
    o1.x = fmaxf(fmaf((float)v[4], scs[c0+4], shs[c0+4]), 0.f);
    o1.y = fmaxf(fmaf((float)v[5], scs[c0+5], shs[c0+5]), 0.f);
    o1.z = fmaxf(fmaf((float)v[6], scs[c0+6], shs[c0+6]), 0.f);
    o1.w = fmaxf(fmaf((float)v[7], scs[c0+7], shs[c0+7]), 0.f);
    float4* op = (float4*)(outbase + 49152);
    op[2*i]   = o0;
    op[2*i+1] = o1;
}

extern "C" void kernel_launch(void* const* d_in, const int* in_sizes, int n_in,
                              void* d_out, int out_size, void* d_ws, size_t ws_size,
                              hipStream_t stream)
{
    const float* xyz = (const float*)d_in[0];
    const float* pts = (const float*)d_in[1];
    const float* w0  = (const float*)d_in[2];
    const float* b0  = (const float*)d_in[3];
    const float* g0  = (const float*)d_in[4];
    const float* bt0 = (const float*)d_in[5];
    const float* w1  = (const float*)d_in[6];
    const float* b1  = (const float*)d_in[7];
    const float* g1  = (const float*)d_in[8];
    const float* bt1 = (const float*)d_in[9];
    const float* w2  = (const float*)d_in[10];
    const float* b2  = (const float*)d_in[11];
    const float* g2  = (const float*)d_in[12];
    const float* bt2 = (const float*)d_in[13];
    float* out = (float*)d_out;

    // Layout: gidx [0,2M) ptsx [2M,4.46M) xm [4.5M,8.5M) y1 [8.5M,12.5M) y2 [12.5M,20.5M)
    //         stats [20.5M,+48K) W [24M,+164K)  ypt @32M (own region — NO aliasing; the
    //         harness re-poison fill is 256MiB, so ws_size comfortably covers 36MB)
    char* ws = (char*)d_ws;
    int*      gidx = (int*)ws;
    half8*    ptsx = (half8*)(ws + 2097152);
    _Float16* xmh  = (_Float16*)(ws + 4718592);
    _Float16* y1h  = (_Float16*)(ws + 8912896);
    _Float16* y2h  = (_Float16*)(ws + 13107200);
    float*    stb  = (float*)(ws + 21495808);        // 12288-float banked BN-stat block
    float *s0a = stb,        *q0a = stb + 2048;      // 16 banks x 128, layer0 count 524288
    float *s1a = stb + 4096, *q1a = stb + 6144;      // 16 banks x 128, layer1 count 16384
    float *s2a = stb + 8192, *q2a = stb + 10240;     // 8 banks x 256, layer2 count 16384
    char*     wb   = ws + (24u << 20);
    half8*    w0fA = (half8*)wb;                     // 16384 B
    half8*    w0fB = (half8*)(wb + 16384);           // 2176 B (ends 18560)
    float4*   wcq  = (float4*)(wb + 20480);          // 2048 B (in the w0fB..w1h gap)
    _Float16* w1h  = (_Float16*)(wb + 32768);        // 32768 B
    _Float16* w2h  = (_Float16*)(wb + 98304);        // 65536 B
    // ypt: dedicated 4MB region, disjoint from every other buffer (guarded fallback
    // to the y2h alias only if ws_size were unexpectedly small)
    _Float16* ypt  = (_Float16*)(ws + ((ws_size >= (38u << 20)) ? (size_t)(32u << 20)
                                                                : (size_t)13107200));

    bq_cvt_kernel<<<4725, 256, 0, stream>>>(xyz, pts, w0, w1, w2, b0, gidx, ptsx,
                                            w0fA, w0fB, w1h, w2h, wcq, out, stb);
    ypt_kernel<<<256, 256, 0, stream>>>(ptsx, w0fA, w0fB, ypt);
    pool_stats_kernel<<<1024, 256, 0, stream>>>(ypt, gidx, wcq, xyz, s0a, q0a, xmh);
    conv12_mfma_kernel<128, NB1><<<dim3(64,1,4), 256, 0, stream>>>(xmh, w1h, b1, s0a, q0a,
                                                                   g0, bt0, 1.f/524288.f,
                                                                   y1h, s1a, q1a);
    conv12_mfma_kernel<256, NB2><<<dim3(64,2,4), 256, 0, stream>>>(y1h, w2h, b2, s1a, q1a,
                                                                   g1, bt1, 1.f/16384.f,
                                                                   y2h, s2a, q2a);
    final_apply_kernel<<<2048, 256, 0, stream>>>(y2h, s2a, q2a, g2, bt2, 1.f/16384.f, out);
}